// Round 1
// baseline (535.947 us; speedup 1.0000x reference)
//
#include <hip/hip_runtime.h>
#include <math.h>

#define NC 19
#define H  320
#define W  2048
#define HW (H * W)         // 655360
#define P  1280            // 10 * 128
#define NB 8

// Kernel 1: argmax_c of 16x16 block sums of raw label (log_softmax + block-mean
// is argmax-equivalent). Only hh in [10,20) survives the slice -> rows 160..319.
// One wave handles TWO adjacent ww blocks: per row a full aligned 128 B segment.
// lane -> r = lane>>3 (8 rows/load, 2 loads/channel), c4 = lane&7 (8 float4).
//
// Restructured vs previous version: loads for all 19 channels are issued in a
// pure load+FADD phase (no cross-lane ops -> deep memory-level parallelism),
// then the 19 independent butterfly chains run back-to-back so their shuffle
// latencies overlap. Per-channel add tree and shuffle order are bit-identical
// to the previous passing kernel -> identical argmax tie behavior.
__global__ __launch_bounds__(256) void pool_argmax_kernel(
    const float* __restrict__ label, int* __restrict__ lab)
{
    int gw   = blockIdx.x * 4 + (threadIdx.x >> 6);   // 0..5119 wave id
    int lane = threadIdx.x & 63;

    int wp = gw & 63;           // ww pair index, blocks 2*wp, 2*wp+1
    int t  = gw >> 6;           // b*10 + hp
    int hp = t % 10;
    int b  = t / 10;

    int h0 = (hp + 10) * 16;    // rows 160..319 only
    int w0 = wp * 32;           // 2 blocks = 32 floats = 128 B

    int r  = lane >> 3;         // 0..7
    int c4 = lane & 7;          // 0..7 float4 within 128 B row segment

    const float* p0 = label + (size_t)b * NC * HW + (size_t)(h0 + r) * W
                    + (size_t)w0 + (size_t)c4 * 4;

    // Phase 1: per-lane partial sums for all channels. 38 independent float4
    // loads -> BW-bound streaming.
    float sc[NC];
    #pragma unroll
    for (int c = 0; c < NC; ++c) {
        const float* pc = p0 + (size_t)c * HW;
        float4 v0 = *(const float4*)(pc);            // rows h0+r
        float4 v1 = *(const float4*)(pc + 8 * W);    // rows h0+8+r
        sc[c] = ((v0.x + v0.y) + (v0.z + v0.w))
              + ((v1.x + v1.y) + (v1.z + v1.w));
    }

    // Phase 2: 19 independent butterfly reductions (bits 0,1 = c4 within half,
    // bits 3,4,5 = rows). Chains are independent -> scheduler interleaves.
    float best  = -3.4e38f;
    int   bestc = 0;
    #pragma unroll
    for (int c = 0; c < NC; ++c) {
        float s = sc[c];
        s += __shfl_xor(s, 1, 64);
        s += __shfl_xor(s, 2, 64);
        s += __shfl_xor(s, 8, 64);
        s += __shfl_xor(s, 16, 64);
        s += __shfl_xor(s, 32, 64);
        if (s > best) { best = s; bestc = c; }   // strict > == first-max tie-break
    }
    // lane 0 holds block sub=0 sum, lane 4 holds block sub=1 sum
    if (lane == 0) lab[t * 128 + wp * 2]     = bestc;
    if (lane == 4) lab[t * 128 + wp * 2 + 1] = bestc;
}

// Kernel 2: ONE WAVE per (b, i) row of e / attention_map. 64 lanes x 5 float4
// covers the 1280-wide row. No LDS, no __syncthreads: row max and row sum are
// 6-level wave butterflies. Row max is identical to the previous block max;
// only the sum's reduction tree differs (~1e-7 rel on attn).
__global__ __launch_bounds__(256) void e_softmax_kernel(
    const float* __restrict__ energy, const int* __restrict__ lab,
    float* __restrict__ e_out, float* __restrict__ attn_out)
{
    int row  = blockIdx.x * 4 + (threadIdx.x >> 6);   // 0..10239 = b*1280 + i
    int lane = threadIdx.x & 63;
    int b = row / P;
    int i = row - b * P;

    int li = lab[b * P + i];
    const int4*   lrow = (const int4*)(lab + b * P);
    const float4* erow = (const float4*)(energy + (size_t)row * P);

    float v[20];
    float mx = -3.4e38f;
    #pragma unroll
    for (int k = 0; k < 5; ++k) {
        int idx = lane + 64 * k;
        int4   lj = lrow[idx];
        float4 en = erow[idx];
        int   lv[4] = { lj.x, lj.y, lj.z, lj.w };
        float ev[4] = { en.x, en.y, en.z, en.w };
        #pragma unroll
        for (int m = 0; m < 4; ++m) {
            bool same = (lv[m] == li);
            float x = same ? (ev[m] < 0.f ?  0.5f : ev[m])
                           : (ev[m] > 0.f ? -0.5f : ev[m]);
            v[4 * k + m] = x;
            mx = fmaxf(mx, x);
        }
    }
    #pragma unroll
    for (int off = 32; off; off >>= 1)
        mx = fmaxf(mx, __shfl_xor(mx, off, 64));

    float ex[20];
    float s = 0.f;
    #pragma unroll
    for (int n = 0; n < 20; ++n) { ex[n] = __expf(v[n] - mx); s += ex[n]; }
    #pragma unroll
    for (int off = 32; off; off >>= 1)
        s += __shfl_xor(s, off, 64);
    float inv = 1.0f / s;

    float4* eo = (float4*)(e_out    + (size_t)row * P);
    float4* ao = (float4*)(attn_out + (size_t)row * P);
    #pragma unroll
    for (int k = 0; k < 5; ++k) {
        int idx = lane + 64 * k;
        eo[idx] = make_float4(v[4*k], v[4*k+1], v[4*k+2], v[4*k+3]);
        ao[idx] = make_float4(ex[4*k] * inv, ex[4*k+1] * inv,
                              ex[4*k+2] * inv, ex[4*k+3] * inv);
    }
}

extern "C" void kernel_launch(void* const* d_in, const int* in_sizes, int n_in,
                              void* d_out, int out_size, void* d_ws, size_t ws_size,
                              hipStream_t stream) {
    const float* label  = (const float*)d_in[0];   // [8,19,320,2048] fp32
    const float* energy = (const float*)d_in[1];   // [8,1280,1280]  fp32

    float* e_out    = (float*)d_out;                       // [8,1280,1280]
    float* attn_out = e_out + (size_t)NB * P * P;          // [8,1280,1280]
    int*   lab      = (int*)d_ws;                          // [8,1280]

    hipLaunchKernelGGL(pool_argmax_kernel, dim3(1280), dim3(256), 0, stream,
                       label, lab);
    hipLaunchKernelGGL(e_softmax_kernel, dim3(NB * P / 4), dim3(256), 0, stream,
                       energy, lab, e_out, attn_out);
}